// Round 2
// baseline (1365.486 us; speedup 1.0000x reference)
//
#include <hip/hip_runtime.h>
#include <hip/hip_bf16.h>

// Problem constants (fixed by the reference)
#define NL 48     // dialogue length
#define ND 256    // global feature dim
#define NH 256    // rgcn dim
#define NG 256    // gcn dim
#define NA 128    // attention dim

// ---------------------------------------------------------------------------
// Kernel 1: q = x @ Wq, k = x @ Wk     grid=48, block=128 (one block per row)
// ---------------------------------------------------------------------------
__global__ void qk_kernel(const float* __restrict__ x,
                          const float* __restrict__ Wq,
                          const float* __restrict__ Wk,
                          float* __restrict__ q, float* __restrict__ k) {
    int i = blockIdx.x;
    int a = threadIdx.x;           // 0..127
    __shared__ float xs[ND];
    xs[a]        = x[i * ND + a];
    xs[a + 128]  = x[i * ND + a + 128];
    __syncthreads();
    float accq = 0.f, acck = 0.f;
    #pragma unroll 8
    for (int d = 0; d < ND; ++d) {
        float xv = xs[d];
        accq += xv * Wq[d * NA + a];
        acck += xv * Wk[d * NA + a];
    }
    q[i * NA + a] = accq;
    k[i * NA + a] = acck;
}

// ---------------------------------------------------------------------------
// Kernel 2: scores[i][j] = v . tanh(q_i + k_j); attn = softmax_j
//           grid=48 (one block per query row i), block=64 (single wave)
// ---------------------------------------------------------------------------
__global__ void attn_kernel(const float* __restrict__ q,
                            const float* __restrict__ k,
                            const float* __restrict__ v,
                            float* __restrict__ attn) {
    int i = blockIdx.x;
    int j = threadIdx.x;           // 0..63, j<48 active
    __shared__ float qs[NA];
    __shared__ float vs[NA];
    qs[j]      = q[i * NA + j];
    qs[j + 64] = q[i * NA + j + 64];
    vs[j]      = v[j];
    vs[j + 64] = v[j + 64];
    __syncthreads();

    float s = -INFINITY;
    if (j < NL) {
        float sc = 0.f;
        #pragma unroll 8
        for (int a = 0; a < NA; ++a)
            sc += vs[a] * tanhf(qs[a] + k[j * NA + a]);
        s = sc;
    }
    // wave-wide (64-lane) max
    float m = s;
    for (int off = 32; off; off >>= 1) m = fmaxf(m, __shfl_xor(m, off));
    float e = (j < NL) ? __expf(s - m) : 0.f;
    float tot = e;
    for (int off = 32; off; off >>= 1) tot += __shfl_xor(tot, off);
    if (j < NL) attn[i * NL + j] = e / tot;
}

// ---------------------------------------------------------------------------
// Kernel 3: y[i][c][:] = x[i] @ W_rel[rid(i,c)]   c = s_dst*2 + dir (4 variants)
//           rid = 2*(speaker[i]*48 + s_dst) + dir
//           grid=48*4, block=256
// ---------------------------------------------------------------------------
__global__ void y_kernel(const float* __restrict__ x,
                         const int* __restrict__ speaker,
                         const float* __restrict__ W_rel,
                         float* __restrict__ y) {
    int blk = blockIdx.x;
    int i = blk >> 2;
    int c = blk & 3;               // c = s_dst*2 + dir
    int hh = threadIdx.x;          // 0..255
    __shared__ float xs[ND];
    xs[hh] = x[i * ND + hh];
    __syncthreads();
    int si  = speaker[i];
    int rid = 2 * (si * NL + (c >> 1)) + (c & 1);
    const float* W = W_rel + (size_t)rid * ND * NH;
    float acc = 0.f;
    #pragma unroll 8
    for (int d = 0; d < ND; ++d)
        acc += xs[d] * W[d * NH + hh];
    y[(i * 4 + c) * NH + hh] = acc;
}

// ---------------------------------------------------------------------------
// Kernel 4: h[j] = sum_i attn[i][j] * y[i][c(i,j)] + x[j] @ W_root + b_rgcn
//           c(i,j) = speaker[j]*2 + (i<j ? 0 : 1)
//           grid=48, block=256
// ---------------------------------------------------------------------------
__global__ void h_kernel(const float* __restrict__ x,
                         const int* __restrict__ speaker,
                         const float* __restrict__ W_root,
                         const float* __restrict__ b_rgcn,
                         const float* __restrict__ attn,
                         const float* __restrict__ y,
                         float* __restrict__ h) {
    int j = blockIdx.x;
    int hh = threadIdx.x;          // 0..255
    __shared__ float xs[ND];
    __shared__ float wcol[NL];     // attn[:, j]
    xs[hh] = x[j * ND + hh];
    if (hh < NL) wcol[hh] = attn[hh * NL + j];
    __syncthreads();

    int sj = speaker[j];
    float acc = b_rgcn[hh];
    for (int i = 0; i < NL; ++i) {
        int c = sj * 2 + ((i < j) ? 0 : 1);
        acc += wcol[i] * y[(i * 4 + c) * NH + hh];
    }
    #pragma unroll 8
    for (int d = 0; d < ND; ++d)
        acc += xs[d] * W_root[d * NH + hh];
    h[j * NH + hh] = acc;
}

// ---------------------------------------------------------------------------
// Kernel 5: sumh[:] = sum_j h[j][:]    grid=1, block=256
// ---------------------------------------------------------------------------
__global__ void sumh_kernel(const float* __restrict__ h, float* __restrict__ sumh) {
    int hh = threadIdx.x;
    float acc = 0.f;
    #pragma unroll
    for (int j = 0; j < NL; ++j) acc += h[j * NH + hh];
    sumh[hh] = acc;
}

// ---------------------------------------------------------------------------
// Kernel 6: out[j] = h[j] @ W_self + sumh @ W_nbr + b_gcn    grid=48, block=256
// ---------------------------------------------------------------------------
__global__ void out_kernel(const float* __restrict__ h,
                           const float* __restrict__ sumh,
                           const float* __restrict__ W_self,
                           const float* __restrict__ W_nbr,
                           const float* __restrict__ b_gcn,
                           float* __restrict__ out) {
    int j = blockIdx.x;
    int g = threadIdx.x;           // 0..255
    __shared__ float hs[NH];
    __shared__ float ss[NH];
    hs[g] = h[j * NH + g];
    ss[g] = sumh[g];
    __syncthreads();
    float acc = b_gcn[g];
    #pragma unroll 8
    for (int d = 0; d < NH; ++d) {
        acc += hs[d] * W_self[d * NG + g];
        acc += ss[d] * W_nbr[d * NG + g];
    }
    out[j * NG + g] = acc;
}

// ---------------------------------------------------------------------------
extern "C" void kernel_launch(void* const* d_in, const int* in_sizes, int n_in,
                              void* d_out, int out_size, void* d_ws, size_t ws_size,
                              hipStream_t stream) {
    const float* x      = (const float*)d_in[0];
    const int*   speaker= (const int*)d_in[1];
    const float* Wq     = (const float*)d_in[2];
    const float* Wk     = (const float*)d_in[3];
    const float* v      = (const float*)d_in[4];
    const float* W_rel  = (const float*)d_in[5];
    const float* W_root = (const float*)d_in[6];
    const float* b_rgcn = (const float*)d_in[7];
    const float* W_nbr  = (const float*)d_in[8];
    const float* W_self = (const float*)d_in[9];
    const float* b_gcn  = (const float*)d_in[10];
    float* out = (float*)d_out;

    // workspace layout (fp32)
    float* ws   = (float*)d_ws;
    float* q    = ws;                  // 48*128  = 6144
    float* k    = q    + NL * NA;      // 48*128  = 6144
    float* attn = k    + NL * NA;      // 48*48   = 2304
    float* y    = attn + NL * NL;      // 48*4*256= 49152
    float* h    = y    + NL * 4 * NH;  // 48*256  = 12288
    float* sumh = h    + NL * NH;      // 256

    qk_kernel  <<<NL,     128, 0, stream>>>(x, Wq, Wk, q, k);
    attn_kernel<<<NL,      64, 0, stream>>>(q, k, v, attn);
    y_kernel   <<<NL * 4, 256, 0, stream>>>(x, speaker, W_rel, y);
    h_kernel   <<<NL,     256, 0, stream>>>(x, speaker, W_root, b_rgcn, attn, y, h);
    sumh_kernel<<<1,      256, 0, stream>>>(h, sumh);
    out_kernel <<<NL,     256, 0, stream>>>(h, sumh, W_self, W_nbr, b_gcn, out);
}